// Round 1
// baseline (361.314 us; speedup 1.0000x reference)
//
#include <hip/hip_runtime.h>
#include <hip/hip_bf16.h>

typedef unsigned short u16;
typedef __attribute__((ext_vector_type(8))) short v8s;   // 8 x bf16 (4 VGPRs)
typedef __attribute__((ext_vector_type(4))) float v4f;   // MFMA accum

#define DEV __device__ __forceinline__

DEV u16 f2bf(float f) {
  union { float f; unsigned u; } v; v.f = f;
  unsigned r = v.u + 0x7fffu + ((v.u >> 16) & 1u);  // RNE
  return (u16)(r >> 16);
}

DEV void gload_lds16(const void* g, void* l) {
  __builtin_amdgcn_global_load_lds(
      (const __attribute__((address_space(1))) void*)g,
      (__attribute__((address_space(3))) void*)l, 16, 0, 0);
}

// ---------------- f32 -> bf16 convert (vectorized) ----------------
__global__ __launch_bounds__(256) void cvt_bf16(const float* __restrict__ in,
                                                u16* __restrict__ out, int n4) {
  int i = blockIdx.x * 256 + threadIdx.x;
  if (i >= n4) return;
  float4 v = ((const float4*)in)[i];
  ushort4 o;
  o.x = f2bf(v.x); o.y = f2bf(v.y); o.z = f2bf(v.z); o.w = f2bf(v.w);
  ((ushort4*)out)[i] = o;
}

// ---------------- lambda gates: lam[h][t] = sigmoid(relu(log(t+1)*Wl1+bl1) @ Wl2.T + bl2)
__global__ __launch_bounds__(256) void lam_kernel(const float* __restrict__ Wl1,
    const float* __restrict__ bl1, const float* __restrict__ Wl2,
    const float* __restrict__ bl2, float* __restrict__ lam) {
  int t = blockIdx.x * 256 + threadIdx.x;  // 0..4095
  float lp = logf((float)t + 1.0f);
  float h1[64];
#pragma unroll
  for (int j = 0; j < 64; ++j) h1[j] = fmaxf(lp * Wl1[j] + bl1[j], 0.0f);
#pragma unroll 1
  for (int h = 0; h < 16; ++h) {
    float z = bl2[h];
#pragma unroll
    for (int j = 0; j < 64; ++j) z += h1[j] * Wl2[h * 64 + j];
    lam[h * 4096 + t] = 1.0f / (1.0f + expf(-z));
  }
}

// ---------------- bf16 GEMM: C[M][N] = A[M][K] * Bt[N][K]^T (+bias) ----------------
// 128x128 tile, 4 waves (2x2 of 64x64), BK=32, global_load_lds staging.
template <int OUTF32>
__global__ __launch_bounds__(256) void gemm_bt(const u16* __restrict__ A,
    const u16* __restrict__ Bt, void* __restrict__ Cout,
    const float* __restrict__ bias, int M, int N, int K) {
  __shared__ u16 Asm[128 * 32];
  __shared__ u16 Bsm[128 * 32];
  const int tid = threadIdx.x;
  const int lane = tid & 63;
  const int wid = tid >> 6;
  const int m0 = blockIdx.y * 128;
  const int n0 = blockIdx.x * 128;
  const int wm = (wid >> 1) * 64;
  const int wn = (wid & 1) * 64;
  v4f acc[4][4] = {};

  for (int k0 = 0; k0 < K; k0 += 32) {
    __syncthreads();
#pragma unroll
    for (int j = 0; j < 2; ++j) {
      const int c = j * 256 + tid;          // 16B chunk id, 0..511
      const int row = c >> 2;
      const int col = (c & 3) * 8;
      gload_lds16(A + (size_t)(m0 + row) * K + (k0 + col),
                  &Asm[(j * 256 + (wid << 6)) * 8]);
      gload_lds16(Bt + (size_t)(n0 + row) * K + (k0 + col),
                  &Bsm[(j * 256 + (wid << 6)) * 8]);
    }
    __syncthreads();
    v8s af[4], bfr[4];
#pragma unroll
    for (int mt = 0; mt < 4; ++mt)
      af[mt] = *(const v8s*)&Asm[(wm + mt * 16 + (lane & 15)) * 32 + (lane >> 4) * 8];
#pragma unroll
    for (int nt = 0; nt < 4; ++nt)
      bfr[nt] = *(const v8s*)&Bsm[(wn + nt * 16 + (lane & 15)) * 32 + (lane >> 4) * 8];
#pragma unroll
    for (int mt = 0; mt < 4; ++mt)
#pragma unroll
      for (int nt = 0; nt < 4; ++nt)
        acc[mt][nt] = __builtin_amdgcn_mfma_f32_16x16x32_bf16(af[mt], bfr[nt],
                                                              acc[mt][nt], 0, 0, 0);
  }

  const int r0 = (lane >> 4) * 4;
  const int cc = lane & 15;
#pragma unroll
  for (int mt = 0; mt < 4; ++mt) {
#pragma unroll
    for (int nt = 0; nt < 4; ++nt) {
      const int gr = m0 + wm + mt * 16 + r0;
      const int gc = n0 + wn + nt * 16 + cc;
#pragma unroll
      for (int r = 0; r < 4; ++r) {
        float val = acc[mt][nt][r];
        if (OUTF32) {
          ((float*)Cout)[(size_t)(gr + r) * N + gc] = val + bias[gc];
        } else {
          ((u16*)Cout)[(size_t)(gr + r) * N + gc] = f2bf(val);
        }
      }
    }
  }
}

// ---------------- chunked gated attention ----------------
// One block per (b, h, chunk): Q,K,V are 512x64 bf16 slabs of qkv.
// 8 waves x 16 q-rows x 4 passes. K staged swizzled; V staged transposed.
__global__ __launch_bounds__(512, 2) void attn_chunk(const u16* __restrict__ qkv,
    const float* __restrict__ lam, u16* __restrict__ aout) {
  __shared__ u16 Ksm[512 * 64];   // [key][dim], 128B rows, XOR-swizzled 16B slots
  __shared__ u16 Vt[64 * 520];    // [dim][key], +8 pad per row
  __shared__ float lam_s[512];
  __shared__ u16 p_all[8][16 * 32];

  const int tid = threadIdx.x;
  const int lane = tid & 63;
  const int wid = tid >> 6;
  const int blk = blockIdx.x;          // b*128 + h*8 + c
  const int c = blk & 7;
  const int h = (blk >> 3) & 15;
  const int b = blk >> 7;
  const size_t tok0 = (size_t)b * 4096 + c * 512;
  const u16* qb = qkv + tok0 * 3072 + h * 64;
  const u16* kb = qb + 1024;
  const u16* vb = qb + 2048;

  lam_s[tid] = lam[h * 4096 + c * 512 + tid] * 0.125f;  // fold scale = dh^-0.5

  // stage K with XOR swizzle (pre-swizzled global source, linear LDS dest)
#pragma unroll
  for (int i = 0; i < 8; ++i) {
    const int r = i * 64 + wid * 8 + (lane >> 3);
    const int cb = (lane & 7) ^ (r & 7);
    gload_lds16(kb + (size_t)r * 3072 + cb * 8, &Ksm[(i * 64 + wid * 8) * 64]);
  }
  // stage V transposed (reg-staged, pack 2 keys per 4B write)
  {
    const int pr = tid & 255;            // key pair 2pr, 2pr+1
    const int db0 = (tid >> 8) * 4;      // dim-block half
#pragma unroll
    for (int dbi = 0; dbi < 4; ++dbi) {
      const int d0 = (db0 + dbi) * 8;
      v8s v0 = *(const v8s*)(vb + (size_t)(2 * pr) * 3072 + d0);
      v8s v1 = *(const v8s*)(vb + (size_t)(2 * pr + 1) * 3072 + d0);
#pragma unroll
      for (int j = 0; j < 8; ++j) {
        unsigned pk = (unsigned)(u16)v0[j] | ((unsigned)(u16)v1[j] << 16);
        *(unsigned*)&Vt[(d0 + j) * 520 + 2 * pr] = pk;
      }
    }
  }
  __syncthreads();

  u16* ps = p_all[wid];
#pragma unroll 1
  for (int pass = 0; pass < 4; ++pass) {
    const int q0 = pass * 128 + wid * 16;
    v8s qf[2];
#pragma unroll
    for (int kk = 0; kk < 2; ++kk)
      qf[kk] = *(const v8s*)(qb + (size_t)(q0 + (lane & 15)) * 3072 + kk * 32 + (lane >> 4) * 8);

    // S = Q K^T, gated: 32 tiles of 16x16 held in C-layout
    v4f s[32];
#pragma unroll
    for (int kt = 0; kt < 32; ++kt) {
      v4f z = {0.f, 0.f, 0.f, 0.f};
      const int row = kt * 16 + (lane & 15);
#pragma unroll
      for (int kk = 0; kk < 2; ++kk) {
        const int slot = (kk * 4 + (lane >> 4)) ^ (row & 7);
        v8s kf = *(const v8s*)&Ksm[row * 64 + slot * 8];
        z = __builtin_amdgcn_mfma_f32_16x16x32_bf16(qf[kk], kf, z, 0, 0, 0);
      }
      const float lv = lam_s[kt * 16 + (lane & 15)];
      s[kt] = z * lv;
    }

    // softmax over 512 keys; rows live on 16-lane groups (xor 1,2,4,8)
    float mx[4], sm[4];
#pragma unroll
    for (int r = 0; r < 4; ++r) {
      float m = s[0][r];
#pragma unroll
      for (int kt = 1; kt < 32; ++kt) m = fmaxf(m, s[kt][r]);
#pragma unroll
      for (int x = 1; x < 16; x <<= 1) m = fmaxf(m, __shfl_xor(m, x));
      mx[r] = m;
    }
#pragma unroll
    for (int kt = 0; kt < 32; ++kt) {
#pragma unroll
      for (int r = 0; r < 4; ++r) s[kt][r] = __expf(s[kt][r] - mx[r]);
    }
#pragma unroll
    for (int r = 0; r < 4; ++r) {
      float t = 0.f;
#pragma unroll
      for (int kt = 0; kt < 32; ++kt) t += s[kt][r];
#pragma unroll
      for (int x = 1; x < 16; x <<= 1) t += __shfl_xor(t, x);
      sm[r] = 1.0f / t;  // fold normalization into P staging
    }

    // O^T = V^T * P^T  (A-frag straight from Vt, B-frag from P round-trip)
    v4f o[4] = {};
#pragma unroll
    for (int kp = 0; kp < 16; ++kp) {
#pragma unroll
      for (int t2 = 0; t2 < 2; ++t2) {
#pragma unroll
        for (int r = 0; r < 4; ++r)
          ps[((lane >> 4) * 4 + r) * 32 + t2 * 16 + (lane & 15)] =
              f2bf(s[kp * 2 + t2][r] * sm[r]);
      }
      v8s pf = *(const v8s*)&ps[(lane & 15) * 32 + (lane >> 4) * 8];
#pragma unroll
      for (int dt = 0; dt < 4; ++dt) {
        v8s vf = *(const v8s*)&Vt[(dt * 16 + (lane & 15)) * 520 + kp * 32 + (lane >> 4) * 8];
        o[dt] = __builtin_amdgcn_mfma_f32_16x16x32_bf16(vf, pf, o[dt], 0, 0, 0);
      }
    }

    // write O^T tile: lane's col = q-row (lane&15), rows = 4 consecutive dims
    const size_t obase = (tok0 + q0 + (lane & 15)) * 1024 + h * 64;
#pragma unroll
    for (int dt = 0; dt < 4; ++dt) {
      ushort4 w;
      w.x = f2bf(o[dt][0]); w.y = f2bf(o[dt][1]);
      w.z = f2bf(o[dt][2]); w.w = f2bf(o[dt][3]);
      *(ushort4*)&aout[obase + dt * 16 + (lane >> 4) * 4] = w;
    }
  }
}

extern "C" void kernel_launch(void* const* d_in, const int* in_sizes, int n_in,
                              void* d_out, int out_size, void* d_ws, size_t ws_size,
                              hipStream_t stream) {
  const float* x    = (const float*)d_in[0];
  const float* Wqkv = (const float*)d_in[1];
  const float* Wout = (const float*)d_in[2];
  const float* bout = (const float*)d_in[3];
  const float* Wl1  = (const float*)d_in[4];
  const float* bl1  = (const float*)d_in[5];
  const float* Wl2  = (const float*)d_in[6];
  const float* bl2  = (const float*)d_in[7];
  float* out = (float*)d_out;

  char* ws = (char*)d_ws;
  u16* xbf    = (u16*)ws; ws += (size_t)16384 * 1024 * 2;
  u16* wqkvbf = (u16*)ws; ws += (size_t)3072 * 1024 * 2;
  u16* woutbf = (u16*)ws; ws += (size_t)1024 * 1024 * 2;
  u16* qkvbf  = (u16*)ws; ws += (size_t)16384 * 3072 * 2;
  u16* aoutbf = (u16*)ws; ws += (size_t)16384 * 1024 * 2;
  float* lam  = (float*)ws; ws += (size_t)16 * 4096 * 4;

  cvt_bf16<<<16384, 256, 0, stream>>>(x, xbf, 16777216 / 4);
  cvt_bf16<<<3072, 256, 0, stream>>>(Wqkv, wqkvbf, 3145728 / 4);
  cvt_bf16<<<1024, 256, 0, stream>>>(Wout, woutbf, 1048576 / 4);
  lam_kernel<<<16, 256, 0, stream>>>(Wl1, bl1, Wl2, bl2, lam);

  dim3 g1(3072 / 128, 16384 / 128);
  gemm_bt<0><<<g1, 256, 0, stream>>>(xbf, wqkvbf, qkvbf, nullptr, 16384, 3072, 1024);

  attn_chunk<<<512, 512, 0, stream>>>(qkvbf, lam, aoutbf);

  dim3 g2(1024 / 128, 16384 / 128);
  gemm_bt<1><<<g2, 256, 0, stream>>>(aoutbf, woutbf, out, bout, 16384, 1024, 1024);
}

// Round 2
// 315.068 us; speedup vs baseline: 1.1468x; 1.1468x over previous
//
#include <hip/hip_runtime.h>
#include <hip/hip_bf16.h>

typedef unsigned short u16;
typedef __attribute__((ext_vector_type(8))) short v8s;   // 8 x bf16 (4 VGPRs)
typedef __attribute__((ext_vector_type(4))) float v4f;   // MFMA accum

#define DEV __device__ __forceinline__

DEV u16 f2bf(float f) {
  union { float f; unsigned u; } v; v.f = f;
  unsigned r = v.u + 0x7fffu + ((v.u >> 16) & 1u);  // RNE
  return (u16)(r >> 16);
}

DEV void gload_lds16(const void* g, void* l) {
  __builtin_amdgcn_global_load_lds(
      (const __attribute__((address_space(1))) void*)g,
      (__attribute__((address_space(3))) void*)l, 16, 0, 0);
}

// ---------------- f32 -> bf16 convert (vectorized) ----------------
__global__ __launch_bounds__(256) void cvt_bf16(const float* __restrict__ in,
                                                u16* __restrict__ out, int n4) {
  int i = blockIdx.x * 256 + threadIdx.x;
  if (i >= n4) return;
  float4 v = ((const float4*)in)[i];
  ushort4 o;
  o.x = f2bf(v.x); o.y = f2bf(v.y); o.z = f2bf(v.z); o.w = f2bf(v.w);
  ((ushort4*)out)[i] = o;
}

// ---------------- lambda gates ----------------
__global__ __launch_bounds__(256) void lam_kernel(const float* __restrict__ Wl1,
    const float* __restrict__ bl1, const float* __restrict__ Wl2,
    const float* __restrict__ bl2, float* __restrict__ lam) {
  int t = blockIdx.x * 256 + threadIdx.x;  // 0..4095
  float lp = logf((float)t + 1.0f);
  float h1[64];
#pragma unroll
  for (int j = 0; j < 64; ++j) h1[j] = fmaxf(lp * Wl1[j] + bl1[j], 0.0f);
#pragma unroll 1
  for (int h = 0; h < 16; ++h) {
    float z = bl2[h];
#pragma unroll
    for (int j = 0; j < 64; ++j) z += h1[j] * Wl2[h * 64 + j];
    lam[h * 4096 + t] = 1.0f / (1.0f + expf(-z));
  }
}

// ---------------- 256x256 8-phase bf16 GEMM ----------------
// C[M][N] = A[M][K] * Bt[N][K]^T (+bias). BK=64, 8 waves (2Mx4N),
// 128 KiB LDS double-buffer, XOR slot-swizzle, counted vmcnt(6), setprio.
template <int MH, int NH>
DEV void mfma16(v4f (&acc)[8][4], const v8s (&a)[4][2], const v8s (&b)[2][2]) {
#pragma unroll
  for (int kk = 0; kk < 2; ++kk)
#pragma unroll
    for (int i = 0; i < 4; ++i)
#pragma unroll
      for (int j = 0; j < 2; ++j)
        acc[MH * 4 + i][NH * 2 + j] = __builtin_amdgcn_mfma_f32_16x16x32_bf16(
            a[i][kk], b[j][kk], acc[MH * 4 + i][NH * 2 + j], 0, 0, 0);
}

DEV void ldA(v8s (&a)[4][2], const u16* Ab, int wr, int mh, int lane) {
  const int l15 = lane & 15, g = lane >> 4;
#pragma unroll
  for (int i = 0; i < 4; ++i) {
    const int row = wr * 128 + mh * 64 + i * 16 + l15;
#pragma unroll
    for (int kk = 0; kk < 2; ++kk)
      a[i][kk] = *(const v8s*)(Ab + row * 64 + (((kk * 4 + g) ^ (row & 7)) << 3));
  }
}

DEV void ldB(v8s (&b)[2][2], const u16* Bb, int wc, int nh, int lane) {
  const int l15 = lane & 15, g = lane >> 4;
#pragma unroll
  for (int j = 0; j < 2; ++j) {
    const int row = nh * 128 + wc * 32 + j * 16 + l15;
#pragma unroll
    for (int kk = 0; kk < 2; ++kk)
      b[j][kk] = *(const v8s*)(Bb + row * 64 + (((kk * 4 + g) ^ (row & 7)) << 3));
  }
}

template <int OUTF32>
__global__ __launch_bounds__(512, 2) void gemm256(const u16* __restrict__ A,
    const u16* __restrict__ Bt, void* __restrict__ Cout,
    const float* __restrict__ bias, int M, int N, int K) {
  __shared__ u16 As[2][256 * 64];
  __shared__ u16 Bs[2][256 * 64];
  const int tid = threadIdx.x;
  const int lane = tid & 63;
  const int nbn = N >> 8;
  const int nwg = gridDim.x;
  int wg = blockIdx.x;
  wg = (wg & 7) * (nwg >> 3) + (wg >> 3);   // XCD swizzle (nwg % 8 == 0)
  const int m0 = (wg / nbn) << 8;
  const int n0 = (wg % nbn) << 8;
  const int wid = tid >> 6;
  const int wr = wid >> 2;   // 0..1
  const int wc = wid & 3;    // 0..3
  const int nkt = K >> 6;
  const int nit = nkt >> 1;

  // staging: linear LDS dest, inverse-swizzled global source (rule #21)
  auto SAu = [&](int buf, int kt, int u) {
    const int ur = tid >> 3;                       // LDS row within unit
    const int slot = (tid & 7) ^ (ur & 7);
    gload_lds16(A + (size_t)(m0 + u * 64 + ur) * K + kt * 64 + slot * 8,
                &As[buf][u * 4096 + (tid & ~63) * 8]);
  };
  auto SBu = [&](int buf, int kt, int u) {
    const int q = tid >> 3;
    const int grow = (((u & 1) * 2 + (q >> 5)) << 6) + ((u >> 1) << 5) + (q & 31);
    const int slot = (tid & 7) ^ (q & 7);
    gload_lds16(Bt + (size_t)(n0 + grow) * K + kt * 64 + slot * 8,
                &Bs[buf][u * 4096 + (tid & ~63) * 8]);
  };
  auto SA_ = [&](int buf, int kt, int mh) { SAu(buf, kt, mh); SAu(buf, kt, 2 + mh); };
  auto SB_ = [&](int buf, int kt, int nh) { SBu(buf, kt, nh * 2); SBu(buf, kt, nh * 2 + 1); };

  v4f acc[8][4] = {};
  v8s a[4][2], b[2][2];

  // prologue: tile0 complete (8 loads) + tile1 {A-mh0, B-nh1, A-mh1} (6 loads)
  SA_(0, 0, 0); SB_(0, 0, 0); SB_(0, 0, 1); SA_(0, 0, 1);
  SA_(1, 1 < nkt ? 1 : 0, 0); SB_(1, 1 < nkt ? 1 : 0, 1); SA_(1, 1 < nkt ? 1 : 0, 1);
  asm volatile("s_waitcnt vmcnt(6)" ::: "memory");
  asm volatile("s_barrier" ::: "memory");

#define PHASE(MHc, NHc, STAGE, VM)                      \
  STAGE;                                                \
  asm volatile("s_barrier" ::: "memory");               \
  __builtin_amdgcn_sched_barrier(0);                    \
  __builtin_amdgcn_s_setprio(1);                        \
  mfma16<MHc, NHc>(acc, a, b);                          \
  __builtin_amdgcn_s_setprio(0);                        \
  if (VM) asm volatile("s_waitcnt vmcnt(6)" ::: "memory"); \
  asm volatile("s_barrier" ::: "memory");

  for (int it = 0; it < nit; ++it) {
    const int t0 = 2 * it;
    const int tn = t0 + 1;
    const int ta = (t0 + 2 < nkt) ? t0 + 2 : nkt - 1;
    const int tb = (t0 + 3 < nkt) ? t0 + 3 : nkt - 1;
    // P1: quadrant (0,0) of buf0
    ldA(a, As[0], wr, 0, lane); ldB(b, Bs[0], wc, 0, lane);
    PHASE(0, 0, SB_(1, tn, 0), 0);
    // P2: (0,1) — reuse a
    ldB(b, Bs[0], wc, 1, lane);
    PHASE(0, 1, SA_(0, ta, 0), 0);
    // P3: (1,1) — reuse b
    ldA(a, As[0], wr, 1, lane);
    PHASE(1, 1, SB_(0, ta, 1), 0);
    // P4: (1,0) — reuse a
    ldB(b, Bs[0], wc, 0, lane);
    PHASE(1, 0, SA_(0, ta, 1), 1);
    // P5: (0,0) of buf1
    ldA(a, As[1], wr, 0, lane); ldB(b, Bs[1], wc, 0, lane);
    PHASE(0, 0, SB_(0, ta, 0), 0);
    // P6
    ldB(b, Bs[1], wc, 1, lane);
    PHASE(0, 1, SA_(1, tb, 0), 0);
    // P7
    ldA(a, As[1], wr, 1, lane);
    PHASE(1, 1, SB_(1, tb, 1), 0);
    // P8
    ldB(b, Bs[1], wc, 0, lane);
    PHASE(1, 0, SA_(1, tb, 1), 1);
  }
#undef PHASE

  // epilogue: C/D layout col=lane&15, row=(lane>>4)*4+r (verified convention)
  const int l15 = lane & 15, g4 = (lane >> 4) * 4;
#pragma unroll
  for (int i = 0; i < 8; ++i) {
#pragma unroll
    for (int j = 0; j < 4; ++j) {
      const int gr = m0 + wr * 128 + i * 16 + g4;
      const int gc = n0 + wc * 64 + j * 16 + l15;
      float bv = OUTF32 ? bias[gc] : 0.0f;
#pragma unroll
      for (int r = 0; r < 4; ++r) {
        float val = acc[i][j][r];
        if (OUTF32) ((float*)Cout)[(size_t)(gr + r) * N + gc] = val + bv;
        else ((u16*)Cout)[(size_t)(gr + r) * N + gc] = f2bf(val);
      }
    }
  }
}

// ---------------- chunked gated attention (unchanged) ----------------
__global__ __launch_bounds__(512, 2) void attn_chunk(const u16* __restrict__ qkv,
    const float* __restrict__ lam, u16* __restrict__ aout) {
  __shared__ u16 Ksm[512 * 64];   // [key][dim], XOR-swizzled 16B slots
  __shared__ u16 Vt[64 * 520];    // [dim][key], +8 pad per row
  __shared__ float lam_s[512];
  __shared__ u16 p_all[8][16 * 32];

  const int tid = threadIdx.x;
  const int lane = tid & 63;
  const int wid = tid >> 6;
  const int blk = blockIdx.x;          // b*128 + h*8 + c
  const int c = blk & 7;
  const int h = (blk >> 3) & 15;
  const int b = blk >> 7;
  const size_t tok0 = (size_t)b * 4096 + c * 512;
  const u16* qb = qkv + tok0 * 3072 + h * 64;
  const u16* kb = qb + 1024;
  const u16* vb = qb + 2048;

  lam_s[tid] = lam[h * 4096 + c * 512 + tid] * 0.125f;  // fold scale

#pragma unroll
  for (int i = 0; i < 8; ++i) {
    const int r = i * 64 + wid * 8 + (lane >> 3);
    const int cb = (lane & 7) ^ (r & 7);
    gload_lds16(kb + (size_t)r * 3072 + cb * 8, &Ksm[(i * 64 + wid * 8) * 64]);
  }
  {
    const int pr = tid & 255;
    const int db0 = (tid >> 8) * 4;
#pragma unroll
    for (int dbi = 0; dbi < 4; ++dbi) {
      const int d0 = (db0 + dbi) * 8;
      v8s v0 = *(const v8s*)(vb + (size_t)(2 * pr) * 3072 + d0);
      v8s v1 = *(const v8s*)(vb + (size_t)(2 * pr + 1) * 3072 + d0);
#pragma unroll
      for (int j = 0; j < 8; ++j) {
        unsigned pk = (unsigned)(u16)v0[j] | ((unsigned)(u16)v1[j] << 16);
        *(unsigned*)&Vt[(d0 + j) * 520 + 2 * pr] = pk;
      }
    }
  }
  __syncthreads();

  u16* ps = p_all[wid];
#pragma unroll 1
  for (int pass = 0; pass < 4; ++pass) {
    const int q0 = pass * 128 + wid * 16;
    v8s qf[2];
#pragma unroll
    for (int kk = 0; kk < 2; ++kk)
      qf[kk] = *(const v8s*)(qb + (size_t)(q0 + (lane & 15)) * 3072 + kk * 32 + (lane >> 4) * 8);

    v4f s[32];
#pragma unroll
    for (int kt = 0; kt < 32; ++kt) {
      v4f z = {0.f, 0.f, 0.f, 0.f};
      const int row = kt * 16 + (lane & 15);
#pragma unroll
      for (int kk = 0; kk < 2; ++kk) {
        const int slot = (kk * 4 + (lane >> 4)) ^ (row & 7);
        v8s kf = *(const v8s*)&Ksm[row * 64 + slot * 8];
        z = __builtin_amdgcn_mfma_f32_16x16x32_bf16(qf[kk], kf, z, 0, 0, 0);
      }
      const float lv = lam_s[kt * 16 + (lane & 15)];
      s[kt] = z * lv;
    }

    float mx[4], sm[4];
#pragma unroll
    for (int r = 0; r < 4; ++r) {
      float m = s[0][r];
#pragma unroll
      for (int kt = 1; kt < 32; ++kt) m = fmaxf(m, s[kt][r]);
#pragma unroll
      for (int x = 1; x < 16; x <<= 1) m = fmaxf(m, __shfl_xor(m, x));
      mx[r] = m;
    }
#pragma unroll
    for (int kt = 0; kt < 32; ++kt) {
#pragma unroll
      for (int r = 0; r < 4; ++r) s[kt][r] = __expf(s[kt][r] - mx[r]);
    }
#pragma unroll
    for (int r = 0; r < 4; ++r) {
      float t = 0.f;
#pragma unroll
      for (int kt = 0; kt < 32; ++kt) t += s[kt][r];
#pragma unroll
      for (int x = 1; x < 16; x <<= 1) t += __shfl_xor(t, x);
      sm[r] = 1.0f / t;
    }

    v4f o[4] = {};
#pragma unroll
    for (int kp = 0; kp < 16; ++kp) {
#pragma unroll
      for (int t2 = 0; t2 < 2; ++t2) {
#pragma unroll
        for (int r = 0; r < 4; ++r)
          ps[((lane >> 4) * 4 + r) * 32 + t2 * 16 + (lane & 15)] =
              f2bf(s[kp * 2 + t2][r] * sm[r]);
      }
      v8s pf = *(const v8s*)&ps[(lane & 15) * 32 + (lane >> 4) * 8];
#pragma unroll
      for (int dt = 0; dt < 4; ++dt) {
        v8s vf = *(const v8s*)&Vt[(dt * 16 + (lane & 15)) * 520 + kp * 32 + (lane >> 4) * 8];
        o[dt] = __builtin_amdgcn_mfma_f32_16x16x32_bf16(vf, pf, o[dt], 0, 0, 0);
      }
    }

    const size_t obase = (tok0 + q0 + (lane & 15)) * 1024 + h * 64;
#pragma unroll
    for (int dt = 0; dt < 4; ++dt) {
      ushort4 w;
      w.x = f2bf(o[dt][0]); w.y = f2bf(o[dt][1]);
      w.z = f2bf(o[dt][2]); w.w = f2bf(o[dt][3]);
      *(ushort4*)&aout[obase + dt * 16 + (lane >> 4) * 4] = w;
    }
  }
}

extern "C" void kernel_launch(void* const* d_in, const int* in_sizes, int n_in,
                              void* d_out, int out_size, void* d_ws, size_t ws_size,
                              hipStream_t stream) {
  const float* x    = (const float*)d_in[0];
  const float* Wqkv = (const float*)d_in[1];
  const float* Wout = (const float*)d_in[2];
  const float* bout = (const float*)d_in[3];
  const float* Wl1  = (const float*)d_in[4];
  const float* bl1  = (const float*)d_in[5];
  const float* Wl2  = (const float*)d_in[6];
  const float* bl2  = (const float*)d_in[7];
  float* out = (float*)d_out;

  char* ws = (char*)d_ws;
  u16* xbf    = (u16*)ws; ws += (size_t)16384 * 1024 * 2;
  u16* wqkvbf = (u16*)ws; ws += (size_t)3072 * 1024 * 2;
  u16* woutbf = (u16*)ws; ws += (size_t)1024 * 1024 * 2;
  u16* qkvbf  = (u16*)ws; ws += (size_t)16384 * 3072 * 2;
  u16* aoutbf = (u16*)ws; ws += (size_t)16384 * 1024 * 2;
  float* lam  = (float*)ws; ws += (size_t)16 * 4096 * 4;

  cvt_bf16<<<16384, 256, 0, stream>>>(x, xbf, 16777216 / 4);
  cvt_bf16<<<3072, 256, 0, stream>>>(Wqkv, wqkvbf, 3145728 / 4);
  cvt_bf16<<<1024, 256, 0, stream>>>(Wout, woutbf, 1048576 / 4);
  lam_kernel<<<16, 256, 0, stream>>>(Wl1, bl1, Wl2, bl2, lam);

  // QKV projection: 16384x3072x1024, 768 blocks (%8==0)
  gemm256<0><<<dim3((16384 / 256) * (3072 / 256)), 512, 0, stream>>>(
      xbf, wqkvbf, qkvbf, nullptr, 16384, 3072, 1024);

  attn_chunk<<<512, 512, 0, stream>>>(qkvbf, lam, aoutbf);

  // output projection: 16384x1024x1024, 256 blocks (%8==0)
  gemm256<1><<<dim3((16384 / 256) * (1024 / 256)), 512, 0, stream>>>(
      aoutbf, woutbf, out, bout, 16384, 1024, 1024);
}